// Round 8
// baseline (864.028 us; speedup 1.0000x reference)
//
#include <hip/hip_runtime.h>
#include <hip/hip_bf16.h>
#include <cmath>

typedef __hip_bfloat16 bf16;
typedef float v4f __attribute__((ext_vector_type(4)));
typedef short v8s __attribute__((ext_vector_type(8)));   // 8 x bf16 bits
typedef short v4s __attribute__((ext_vector_type(4)));   // 4 x bf16 bits

__device__ __forceinline__ void load_lds16(const void* g, void* l) {
  __builtin_amdgcn_global_load_lds(
      (const __attribute__((address_space(1))) char*)g,
      (__attribute__((address_space(3))) char*)l, 16, 0, 0);
}
__device__ __forceinline__ v4f mfma16x16x32(v8s a, v8s b, v4f c) {
  return __builtin_amdgcn_mfma_f32_16x16x32_bf16(a, b, c, 0, 0, 0);
}
__device__ __forceinline__ v4f mfma16x16x16(v4s a, v4s b, v4f c) {
#if __has_builtin(__builtin_amdgcn_mfma_f32_16x16x16_bf16)
  return __builtin_amdgcn_mfma_f32_16x16x16_bf16(a, b, c, 0, 0, 0);
#elif __has_builtin(__builtin_amdgcn_mfma_f32_16x16x16bf16_1k)
  return __builtin_amdgcn_mfma_f32_16x16x16bf16_1k(a, b, c, 0, 0, 0);
#else
  v4f d;
  asm("v_mfma_f32_16x16x16_bf16 %0, %1, %2, %3"
      : "=v"(d) : "v"(a), "v"(b), "v"(c));
  return d;
#endif
}
__device__ __forceinline__ float b2f(bf16 x) { return __bfloat162float(x); }
__device__ __forceinline__ bf16 f2b(float x) { return __float2bfloat16(x); }
__device__ __forceinline__ ushort b2u(float x) {
  bf16 h = f2b(x);
  return *(ushort*)&h;
}
__device__ __forceinline__ float fexp2(float x) {
#if __has_builtin(__builtin_amdgcn_exp2f)
  return __builtin_amdgcn_exp2f(x);
#else
  return exp2f(x);
#endif
}
__device__ __forceinline__ float gelu_exact(float x) {
  return 0.5f * x * (1.0f + erff(x * 0.70710678118654752f));
}
__device__ __forceinline__ float finz(float v, float sent) {
  return __builtin_isfinite(v) ? v : sent;
}
__device__ __forceinline__ float u2f(ushort u) {
  return __uint_as_float(((unsigned)u) << 16);
}
__device__ __forceinline__ float4 load4f(const float* p) {
  return *(const float4*)p;
}
__device__ __forceinline__ float4 load4f(const bf16* p) {
  ushort4 u = *(const ushort4*)p;
  return make_float4(u2f(u.x), u2f(u.y), u2f(u.z), u2f(u.w));
}

// ---------------------------------------------------------------------------
// LayerNorm: one block per row of 1024, fp32 stats, bf16 out.
// ---------------------------------------------------------------------------
template <typename TI>
__global__ __launch_bounds__(256)
void ln_kernel(const TI* __restrict__ x, const float* __restrict__ g,
               const float* __restrict__ b, bf16* __restrict__ out) {
  __shared__ float red[8];
  __shared__ float stat[2];
  const int row = blockIdx.x, t = threadIdx.x;
  const int wave = t >> 6, lane = t & 63;
  float4 v = load4f(x + (long)row * 1024 + t * 4);
  float s = v.x + v.y + v.z + v.w;
  float s2 = v.x * v.x + v.y * v.y + v.z * v.z + v.w * v.w;
#pragma unroll
  for (int off = 32; off > 0; off >>= 1) {
    s += __shfl_down(s, off);
    s2 += __shfl_down(s2, off);
  }
  if (lane == 0) { red[wave * 2] = s; red[wave * 2 + 1] = s2; }
  __syncthreads();
  if (t == 0) {
    float S = red[0] + red[2] + red[4] + red[6];
    float S2 = red[1] + red[3] + red[5] + red[7];
    float mean = S * (1.0f / 1024.0f);
    float var = S2 * (1.0f / 1024.0f) - mean * mean;
    stat[0] = mean;
    stat[1] = rsqrtf(var + 1e-5f);
  }
  __syncthreads();
  const float mean = stat[0], rs = stat[1];
  bf16* orow = out + (long)row * 1024;
  const int c = t * 4;
  float4 gg = *(const float4*)(g + c);
  float4 bb = *(const float4*)(b + c);
  orow[c + 0] = f2b(finz((v.x - mean) * rs * gg.x + bb.x, 3000.f));
  orow[c + 1] = f2b(finz((v.y - mean) * rs * gg.y + bb.y, 3000.f));
  orow[c + 2] = f2b(finz((v.z - mean) * rs * gg.z + bb.z, 3000.f));
  orow[c + 3] = f2b(finz((v.w - mean) * rs * gg.w + bb.w, 3000.f));
}

// ---------------------------------------------------------------------------
// Repack Wq/Wk/Wv fp32 [H=16, D=1024, HD=64] -> bf16 Wt[n=h*64+kk][d]
// ---------------------------------------------------------------------------
__global__ __launch_bounds__(256)
void repack_qkv(const float* __restrict__ w, bf16* __restrict__ wt) {
  long i = (long)blockIdx.x * 256 + threadIdx.x;
  int n = (int)(i >> 10), d = (int)(i & 1023);
  int h = n >> 6, kk = n & 63;
  wt[i] = f2b(w[((long)h * 1024 + d) * 64 + kk]);
}

// ---------------------------------------------------------------------------
// Tiled transpose fp32 -> bf16: out[c*R + r] = in[r*C + c]
// ---------------------------------------------------------------------------
__global__ __launch_bounds__(256)
void transpose_f2b(const float* __restrict__ in, bf16* __restrict__ out,
                   int R, int C) {
  __shared__ float tile[32][33];
  const int tx = threadIdx.x & 31, ty = threadIdx.x >> 5;
  const int r0 = blockIdx.y * 32, c0 = blockIdx.x * 32;
#pragma unroll
  for (int i = ty; i < 32; i += 8) tile[i][tx] = in[(long)(r0 + i) * C + c0 + tx];
  __syncthreads();
#pragma unroll
  for (int i = ty; i < 32; i += 8)
    out[(long)(c0 + i) * R + r0 + tx] = f2b(tile[tx][i]);
}

// ---------------------------------------------------------------------------
// GEMM C[M,N] = A[M,K] @ Bt[N,K]^T (128x128, BK=32, async global_load_lds).
// EPI: 0=+bias -> bf16
//      1=+bias + fp32 resid -> FP32 (x1 into d_out)
//      2=gelu(+bias) + fp32 resid -> FP32 (in-place on d_out)
//      3=QKV scatter: q (PRE-SCALED by 0.125*log2e), k -> [B,H,S,64];
//        v -> TRANSPOSED [B,H,64,S]
// ---------------------------------------------------------------------------
template <int EPI>
__global__ __launch_bounds__(256)
void gemm_bt(const bf16* __restrict__ A, const bf16* __restrict__ Bt,
             const float* __restrict__ bias0, const float* __restrict__ bias1,
             const float* __restrict__ bias2, const void* __restrict__ residv,
             void* __restrict__ C0v, bf16* __restrict__ C1, bf16* __restrict__ C2v,
             int M, int N, int K) {
  __shared__ bf16 As[128 * 32];
  __shared__ bf16 Bs[128 * 32];
  const int t = threadIdx.x;
  const int wave = t >> 6, lane = t & 63, quad = lane >> 4, ln = lane & 15;
  const int m0 = blockIdx.y * 128, n0 = blockIdx.x * 128;
  const int wm = (wave >> 1) * 64, wn = (wave & 1) * 64;

  v4f acc[4][4];
#pragma unroll
  for (int i = 0; i < 4; i++)
#pragma unroll
    for (int j = 0; j < 4; j++) acc[i][j] = v4f{0.f, 0.f, 0.f, 0.f};

  const int e0 = t * 8, e1 = t * 8 + 2048;
  const int ra0 = e0 >> 5, ca0 = e0 & 31, ra1 = e1 >> 5, ca1 = e1 & 31;
  const bf16* Ab = A + (long)m0 * K;
  const bf16* Bb = Bt + (long)n0 * K;

  for (int k0 = 0; k0 < K; k0 += 32) {
    __syncthreads();
    load_lds16(Ab + (long)ra0 * K + k0 + ca0, &As[e0]);
    load_lds16(Ab + (long)ra1 * K + k0 + ca1, &As[e1]);
    load_lds16(Bb + (long)ra0 * K + k0 + ca0, &Bs[e0]);
    load_lds16(Bb + (long)ra1 * K + k0 + ca1, &Bs[e1]);
    __syncthreads();
    v8s af[4], bfr[4];
#pragma unroll
    for (int mi = 0; mi < 4; mi++)
      af[mi] = *(const v8s*)&As[(wm + mi * 16 + ln) * 32 + quad * 8];
#pragma unroll
    for (int ni = 0; ni < 4; ni++)
      bfr[ni] = *(const v8s*)&Bs[(wn + ni * 16 + ln) * 32 + quad * 8];
#pragma unroll
    for (int mi = 0; mi < 4; mi++)
#pragma unroll
      for (int ni = 0; ni < 4; ni++)
        acc[mi][ni] = mfma16x16x32(af[mi], bfr[ni], acc[mi][ni]);
  }

#pragma unroll
  for (int ni = 0; ni < 4; ni++) {
    const int col = n0 + wn + ni * 16 + ln;
    if (EPI == 3) {
      const int proj = col >> 10, w = col & 1023;
      const float* bp = proj == 0 ? bias0 : (proj == 1 ? bias1 : bias2);
      const float bb = bp[w];
      const int hidx = w >> 6, hd = w & 63;
      if (proj == 2) {
        // v transposed: [b*16+h][hd][2048], ushort4-packed along s
#pragma unroll
        for (int mi = 0; mi < 4; mi++) {
          const int row0 = m0 + wm + mi * 16 + quad * 4;
          const int b_ = row0 >> 11, s = row0 & 2047;
          ushort4 pk;
          pk.x = b2u(finz(acc[mi][ni][0] + bb, 1e4f));
          pk.y = b2u(finz(acc[mi][ni][1] + bb, 1e4f));
          pk.z = b2u(finz(acc[mi][ni][2] + bb, 1e4f));
          pk.w = b2u(finz(acc[mi][ni][3] + bb, 1e4f));
          *(ushort4*)((ushort*)C2v +
                      (((long)(b_ * 16 + hidx)) * 64 + hd) * 2048 + s) = pk;
        }
      } else {
        bf16* op = proj == 0 ? (bf16*)C0v : C1;
        const float sc = proj == 0 ? 0.18033688f : 1.0f;  // 0.125*log2(e)
#pragma unroll
        for (int mi = 0; mi < 4; mi++)
#pragma unroll
          for (int r = 0; r < 4; r++) {
            const int row = m0 + wm + mi * 16 + quad * 4 + r;
            const int b_ = row >> 11, s = row & 2047;
            op[(((long)(b_ * 16 + hidx)) * 2048 + s) * 64 + hd] =
                f2b(finz((acc[mi][ni][r] + bb) * sc, 1e4f));
          }
      }
    } else {
      const float bb = bias0[col];
#pragma unroll
      for (int mi = 0; mi < 4; mi++)
#pragma unroll
        for (int r = 0; r < 4; r++) {
          const int row = m0 + wm + mi * 16 + quad * 4 + r;
          float vv = acc[mi][ni][r] + bb;
          if (EPI == 2) {
            vv = gelu_exact(vv);
            vv += ((const float*)residv)[(long)row * N + col];
            ((float*)C0v)[(long)row * N + col] = finz(vv, 1e5f);
          } else if (EPI == 1) {
            vv += ((const float*)residv)[(long)row * N + col];
            ((float*)C0v)[(long)row * N + col] = finz(vv, 2e4f);
          } else {
            ((bf16*)C0v)[(long)row * N + col] = f2b(finz(vv, 4e4f));
          }
        }
    }
  }
}

// ---------------------------------------------------------------------------
// Flash attention v4: grid (16, B*H); 4 waves x 32 q-rows each (1024 blocks
// -> ~4 blocks/CU; round-7's 512-block grid capped occupancy at 2/CU).
// S^T = K·Q^T register softmax (2 shuffles/16-row block); P^T C-layout ==
// 16x16x16 B-operand layout -> PV from registers. No LDS. K frags double-
// buffered; V frags single-buffered (loaded at iter start, used at iter end).
// q pre-scaled by 0.125*log2e. q,k: [B,H,S,64]; vt: [B,H,64,S].
// ---------------------------------------------------------------------------
__global__ __launch_bounds__(256, 3)
void attn_kernel(const bf16* __restrict__ q, const bf16* __restrict__ k,
                 const bf16* __restrict__ vt, bf16* __restrict__ o) {
  const int t = threadIdx.x, wave = t >> 6, lane = t & 63;
  const int quad = lane >> 4, ln = lane & 15;
  const int bh = blockIdx.y;
  const int q0 = blockIdx.x * 128 + wave * 32;
  const long base = (long)bh * (2048 * 64);

  // Q as B-operand frags (register-resident)
  v8s qf[2][2];
#pragma unroll
  for (int mi = 0; mi < 2; mi++)
#pragma unroll
    for (int kc = 0; kc < 2; kc++)
      qf[mi][kc] = *(const v8s*)(q + base + (long)(q0 + mi * 16 + ln) * 64 +
                                 kc * 32 + quad * 8);

  v4f accO[2][4];  // [mi][nh]: O^T tile, col=ln (q-row), row=quad*4+r (hd)
  float m2[2], l[2];
#pragma unroll
  for (int mi = 0; mi < 2; mi++) {
#pragma unroll
    for (int nh = 0; nh < 4; nh++) accO[mi][nh] = v4f{0.f, 0.f, 0.f, 0.f};
    m2[mi] = -1e30f;
    l[mi] = 0.f;
  }

  v8s ka[4][2], kan[4][2];
  v4s va[4][4];
#pragma unroll
  for (int ni = 0; ni < 4; ni++)
#pragma unroll
    for (int kc = 0; kc < 2; kc++)
      ka[ni][kc] = *(const v8s*)(k + base + (long)(ni * 16 + ln) * 64 +
                                 kc * 32 + quad * 8);

  for (int kv0 = 0; kv0 < 2048; kv0 += 64) {
    // V^T frags for this tile (consumed at iter end -> in-iter latency cover)
#pragma unroll
    for (int nh = 0; nh < 4; nh++)
#pragma unroll
      for (int ni = 0; ni < 4; ni++)
        va[nh][ni] = *(const v4s*)(vt + base + (long)(nh * 16 + ln) * 2048 +
                                   kv0 + ni * 16 + quad * 4);
    // prefetch next K tile
    const int kvn = (kv0 + 64 < 2048) ? kv0 + 64 : kv0;
#pragma unroll
    for (int ni = 0; ni < 4; ni++)
#pragma unroll
      for (int kc = 0; kc < 2; kc++)
        kan[ni][kc] = *(const v8s*)(k + base +
                                    (long)(kvn + ni * 16 + ln) * 64 +
                                    kc * 32 + quad * 8);

#pragma unroll
    for (int mi = 0; mi < 2; mi++) {
      // S^T: lane holds key = ni*16 + quad*4 + r, qrow = mi*16 + ln
      v4f st[4];
#pragma unroll
      for (int ni = 0; ni < 4; ni++) {
        v4f z = v4f{0.f, 0.f, 0.f, 0.f};
        z = mfma16x16x32(ka[ni][0], qf[mi][0], z);
        st[ni] = mfma16x16x32(ka[ni][1], qf[mi][1], z);
      }
      float mx = st[0][0];
#pragma unroll
      for (int ni = 0; ni < 4; ni++)
#pragma unroll
        for (int r = 0; r < 4; r++) mx = fmaxf(mx, st[ni][r]);
      mx = fmaxf(mx, __shfl_xor(mx, 16));
      mx = fmaxf(mx, __shfl_xor(mx, 32));
      const float mo = m2[mi];
      const float mn = fmaxf(mo, mx);
      const float al = fexp2(mo - mn);
      m2[mi] = mn;
      l[mi] *= al;
#pragma unroll
      for (int nh = 0; nh < 4; nh++)
#pragma unroll
        for (int r = 0; r < 4; r++) accO[mi][nh][r] *= al;
      float rs = 0.f;
      v4s pf[4];
#pragma unroll
      for (int ni = 0; ni < 4; ni++) {
        v4s p4;
#pragma unroll
        for (int r = 0; r < 4; r++) {
          float p = fexp2(st[ni][r] - mn);
          rs += p;
          p4[r] = (short)b2u(p);
        }
        pf[ni] = p4;
      }
      rs += __shfl_xor(rs, 16);
      rs += __shfl_xor(rs, 32);
      l[mi] += rs;
#pragma unroll
      for (int nh = 0; nh < 4; nh++)
#pragma unroll
        for (int ni = 0; ni < 4; ni++)
          accO[mi][nh] = mfma16x16x16(va[nh][ni], pf[ni], accO[mi][nh]);
    }
#pragma unroll
    for (int ni = 0; ni < 4; ni++)
#pragma unroll
      for (int kc = 0; kc < 2; kc++) ka[ni][kc] = kan[ni][kc];
  }

  // epilogue: o[b][s=q0+mi*16+ln][h*64 + nh*16+quad*4+r] = accO/l
  const int b_ = bh >> 4, h_ = bh & 15;
#pragma unroll
  for (int mi = 0; mi < 2; mi++) {
    const float inv = 1.0f / l[mi];
    const int s = q0 + mi * 16 + ln;
#pragma unroll
    for (int nh = 0; nh < 4; nh++) {
      ushort4 pk;
      pk.x = b2u(finz(accO[mi][nh][0] * inv, 5000.f));
      pk.y = b2u(finz(accO[mi][nh][1] * inv, 5000.f));
      pk.z = b2u(finz(accO[mi][nh][2] * inv, 5000.f));
      pk.w = b2u(finz(accO[mi][nh][3] * inv, 5000.f));
      *(ushort4*)((ushort*)o + ((long)(b_ * 2048 + s)) * 1024 + h_ * 64 +
                  nh * 16 + quad * 4) = pk;
    }
  }
}

// ---------------------------------------------------------------------------
extern "C" void kernel_launch(void* const* d_in, const int* in_sizes, int n_in,
                              void* d_out, int out_size, void* d_ws,
                              size_t ws_size, hipStream_t stream) {
  const float* x   = (const float*)d_in[0];
  const float* Wq  = (const float*)d_in[1];
  const float* bq  = (const float*)d_in[2];
  const float* Wk  = (const float*)d_in[3];
  const float* bk  = (const float*)d_in[4];
  const float* Wv  = (const float*)d_in[5];
  const float* bv  = (const float*)d_in[6];
  const float* Wo  = (const float*)d_in[7];
  const float* bo  = (const float*)d_in[8];
  const float* W1  = (const float*)d_in[9];
  const float* b1  = (const float*)d_in[10];
  const float* W2  = (const float*)d_in[11];
  const float* b2  = (const float*)d_in[12];
  const float* g1  = (const float*)d_in[13];
  const float* be1 = (const float*)d_in[14];
  const float* g2  = (const float*)d_in[15];
  const float* be2 = (const float*)d_in[16];
  float* out = (float*)d_out;

  const size_t MB = 1024 * 1024;
  if (ws_size < 104 * MB) return;
  char* W = (char*)d_ws;
  bf16* wqt = (bf16*)(W + 0 * MB);
  bf16* wkt = (bf16*)(W + 2 * MB);
  bf16* wvt = (bf16*)(W + 4 * MB);
  bf16* wot = (bf16*)(W + 6 * MB);
  bf16* h   = (bf16*)(W + 8 * MB);    // [8,24)  LN1 out; later LN2 out
  bf16* qb  = (bf16*)(W + 24 * MB);   // [24,40) dead after attn
  bf16* kb  = (bf16*)(W + 40 * MB);   // [40,56) dead after attn
  bf16* vb  = (bf16*)(W + 56 * MB);   // [56,72) v TRANSPOSED [B,H,64,S]
  bf16* ao  = (bf16*)(W + 72 * MB);   // [72,88) dead after Wo-gemm
  bf16* w1t = (bf16*)(W + 24 * MB);   // [24,32) after attn (qb slot)
  bf16* w2t = (bf16*)(W + 32 * MB);   // [32,40)
  bf16* tbc = (bf16*)(W + 40 * MB);   // [40,104) FFN mid [8192][4096] = 64MB
  // x1 lives in d_out as fp32 (in-place resid in final gemm)

  repack_qkv<<<4096, 256, 0, stream>>>(Wq, wqt);
  repack_qkv<<<4096, 256, 0, stream>>>(Wk, wkt);
  repack_qkv<<<4096, 256, 0, stream>>>(Wv, wvt);
  transpose_f2b<<<dim3(32, 32), 256, 0, stream>>>(Wo, wot, 1024, 1024);

  // 1) h = LN1(x)
  ln_kernel<float><<<8192, 256, 0, stream>>>(x, g1, be1, h);
  // 2) q,k,v = h @ Wqkv + b  (q scaled; q,k -> [B,H,S,64]; v -> [B,H,64,S])
  gemm_bt<3><<<dim3(24, 64), 256, 0, stream>>>(h, wqt, bq, bk, bv, nullptr,
                                               qb, kb, vb, 8192, 3072, 1024);
  // 3) flash attention -> ao [B,S,D] bf16
  attn_kernel<<<dim3(16, 64), 256, 0, stream>>>(qb, kb, vb, ao);
  // 4) x1 = x + ao @ Wo + bo  -> FP32 in d_out
  gemm_bt<1><<<dim3(8, 64), 256, 0, stream>>>(ao, wot, bo, nullptr, nullptr, x,
                                              out, nullptr, nullptr, 8192, 1024, 1024);
  transpose_f2b<<<dim3(128, 32), 256, 0, stream>>>(W1, w1t, 1024, 4096);
  transpose_f2b<<<dim3(32, 128), 256, 0, stream>>>(W2, w2t, 4096, 1024);
  // 5) h2 = LN2(x1)  (fp32 in from d_out, bf16 out into h slot)
  ln_kernel<float><<<8192, 256, 0, stream>>>(out, g2, be2, h);
  // 6) tbc = h2 @ W1 + b1   (full M, un-chunked)
  gemm_bt<0><<<dim3(32, 64), 256, 0, stream>>>(h, w1t, b1, nullptr, nullptr,
                                               nullptr, tbc, nullptr, nullptr,
                                               8192, 4096, 1024);
  // 7) out = x1 + gelu(tbc @ W2 + b2)  (in-place fp32 resid on d_out)
  gemm_bt<2><<<dim3(8, 64), 256, 0, stream>>>(tbc, w2t, b2, nullptr, nullptr,
                                              out, out, nullptr, nullptr,
                                              8192, 1024, 4096);
}